// Round 7
// baseline (132.528 us; speedup 1.0000x reference)
//
#include <hip/hip_runtime.h>
#include <stdint.h>

// QuantizedPatternMatcher — R22: bitplane popcount, lane-pair split so the
// ENTIRE live set fits the 64-VGPR tier the allocator insists on.
//
// R21 post-mortem: VMEM path worked (match 99.5 -> 56.8us, clean counters)
// but VGPR_Count=64 vs live set ~110 (rp48+A24+B24) => scratch/remat (L2-
// resident, invisible to FETCH_SIZE), VALUBusy 34%. Third time the backend
// clamps this kernel to 64 regs (R16:128, R17:64, R21:64) regardless of
// hints => DESIGN RULE: fit 64.
//
// R22: thread = (row, half). Even lane: chunks 0-7; odd lane: chunks 8-15.
//  - rp[24] + sp[24] + misc ~= 58 regs < 64: no spill, 8 waves/SIMD.
//  - TLP (32 waves/CU) replaces the register-hungry ILP pipeline: 8 waves x
//    ~42% naive duty saturates the VALU pipe.
//  - per pattern per lane: 6 VMEM dwordx4 (opaque-zero VGPR keeps the
//    uniformity pass off the scalar path; 2 addrs/wave -> 2 vL1 requests)
//    + 48 int VALU (3 xor + 2 or + 1 bcnt-acc per chunk) + 1 shfl_xor to
//    combine halves (~6cyc DS, negligible).
//  - grid 1024 = 32 row-blocks x 32 pattern-tiles, pc fast-varying: blocks
//    spaced 256 (co-resident) share one 6KB vL1-hot tile.
// R20 calibration: VALU ~4.2cyc/instr @4 waves/SIMD; at 8 waves/SIMD expect
// ~2-3 => match ~20-28us. Argmax = min-key (mis<<10)|pat via atomicMin
// (exact ref tie-break). Integer-exact end to end.
#define NROW 8192
#define NPAT 1024

typedef unsigned int u32;
typedef unsigned char u8;

__device__ __forceinline__ u32 bin7(float v, float e0, float e1, float e2,
                                    float e3, float e4, float e5, float e6) {
  return (u32)((v > e0) + (v > e1) + (v > e2) + (v > e3) + (v > e4) +
               (v > e5) + (v > e6));
}

__device__ __forceinline__ void acc3(u32 b, int k, u32& p0, u32& p1, u32& p2) {
  p0 |= (b & 1u) << k;
  p1 |= ((b >> 1) & 1u) << k;
  p2 |= ((b >> 2) & 1u) << k;
}

// ---------------------------------------------------------------------------
// prep: quantize + pack bitplanes; init keys (=0xFFFFFFFF).
//   xplanes [8192][16][3] u32   (48 dwords = 192 B per row; per 32-dim chunk
//   pplanes [1024][16][3] u32    the 3 planes are contiguous)
// ---------------------------------------------------------------------------
__global__ __launch_bounds__(256) void prep_pc(
    const float* __restrict__ x, const float* __restrict__ patterns,
    const float* __restrict__ edges, u32* __restrict__ xplanes,
    u32* __restrict__ pplanes, u32* __restrict__ keys) {
  const int bid = blockIdx.x, tid = threadIdx.x;
  if (bid >= 576) {  // 32 blocks: init keys
    const int r = (bid - 576) * 256 + tid;
    keys[r] = 0xFFFFFFFFu;
    return;
  }
  const float e0 = edges[0], e1 = edges[1], e2 = edges[2], e3 = edges[3],
              e4 = edges[4], e5 = edges[5], e6 = edges[6];
  const float4* s4;
  u32* dst;
  if (bid < 512) {  // x: 8192 rows * 16 chunks
    const int i = bid * 256 + tid;
    s4 = reinterpret_cast<const float4*>(x + (size_t)i * 32);
    dst = xplanes + (size_t)i * 3;
  } else {  // patterns: 1024 * 16
    const int j = (bid - 512) * 256 + tid;
    s4 = reinterpret_cast<const float4*>(patterns + (size_t)j * 32);
    dst = pplanes + (size_t)j * 3;
  }
  u32 p0 = 0, p1 = 0, p2 = 0;
#pragma unroll
  for (int q = 0; q < 8; ++q) {
    const float4 a = s4[q];
    acc3(bin7(a.x, e0, e1, e2, e3, e4, e5, e6), q * 4 + 0, p0, p1, p2);
    acc3(bin7(a.y, e0, e1, e2, e3, e4, e5, e6), q * 4 + 1, p0, p1, p2);
    acc3(bin7(a.z, e0, e1, e2, e3, e4, e5, e6), q * 4 + 2, p0, p1, p2);
    acc3(bin7(a.w, e0, e1, e2, e3, e4, e5, e6), q * 4 + 3, p0, p1, p2);
  }
  dst[0] = p0;
  dst[1] = p1;
  dst[2] = p2;
}

// ---------------------------------------------------------------------------
// match: grid 1024 = 32 row-blocks (slow) x 32 pattern-tiles (fast;
// co-resident blocks spaced 256 = 0 mod 32 share the 6KB tile in vL1).
// 512 thr = 8 waves, 4 blocks/CU = 32 waves/CU. Thread = (row, half):
// row = rb*256 + (tid>>1), half = tid&1 (chunks half*8 .. half*8+7).
// rp[24] resident; sp[24] single buffer; live ~58 < 64 VGPRs.
// ---------------------------------------------------------------------------
__global__ __launch_bounds__(512) void match_pc(
    const u32* __restrict__ xplanes, const u32* __restrict__ pplanes,
    u32* __restrict__ keys) {
  const int tid = threadIdx.x;
  const int rb = blockIdx.x >> 5;  // row block, 0..31 (slow)
  const int pc = blockIdx.x & 31;  // pattern tile, 0..31 (fast)
  const int row = rb * 256 + (tid >> 1);
  const int half = tid & 1;

  // Opaque zero in a VGPR: defeats the uniformity pass -> vector loads
  // (in-order vmcnt), never scalar (out-of-order lgkmcnt drain).
  u32 z;
  asm("v_mov_b32 %0, 0" : "=v"(z));

  u32 rp[24];
  {
    const u8* __restrict__ rs =
        reinterpret_cast<const u8*>(xplanes + (size_t)row * 48 + half * 24) +
        z;
#pragma unroll
    for (int j = 0; j < 6; ++j) {
      const uint4 v = *reinterpret_cast<const uint4*>(rs + j * 16);
      rp[j * 4 + 0] = v.x;
      rp[j * 4 + 1] = v.y;
      rp[j * 4 + 2] = v.z;
      rp[j * 4 + 3] = v.w;
    }
  }

  const u8* __restrict__ pz =
      reinterpret_cast<const u8*>(pplanes + (size_t)pc * (32 * 48) +
                                  half * 24) +
      z;

  u32 best = 0xFFFFFFFFu;
  const u32 pb = (u32)(pc << 5);
#pragma unroll 1
  for (int p = 0; p < 32; ++p) {
    u32 sp[24];
#pragma unroll
    for (int j = 0; j < 6; ++j) {  // 6 VMEM dwordx4, 2 addrs/wave -> vL1
      const uint4 v = *reinterpret_cast<const uint4*>(pz + p * 192 + j * 16);
      sp[j * 4 + 0] = v.x;
      sp[j * 4 + 1] = v.y;
      sp[j * 4 + 2] = v.z;
      sp[j * 4 + 3] = v.w;
    }
    u32 mis = 0;
#pragma unroll
    for (int c = 0; c < 8; ++c) {  // 48 int VALU (bcnt has fused add)
      const u32 d = (rp[c * 3 + 0] ^ sp[c * 3 + 0]) |
                    (rp[c * 3 + 1] ^ sp[c * 3 + 1]) |
                    (rp[c * 3 + 2] ^ sp[c * 3 + 2]);
      mis += (u32)__popc(d);
    }
    mis += (u32)__shfl_xor((int)mis, 1, 64);  // combine the two halves
    const u32 key = (mis << 10) | (pb + (u32)p);
    best = key < best ? key : best;
  }
  // Both lanes of a pair hold the same best; both atomicMin the same slot
  // (idempotent, avoids divergence).
  atomicMin(&keys[row], best);
}

__global__ __launch_bounds__(256) void fixup_pc(const u32* __restrict__ keys,
                                                float* __restrict__ out) {
  const int r = blockIdx.x * 256 + threadIdx.x;
  const u32 k = keys[r];
  out[r] = (float)(k & 1023u);
  out[NROW + r] = (float)(512u - (k >> 10)) * (1.0f / 512.0f);
}

extern "C" void kernel_launch(void* const* d_in, const int* in_sizes, int n_in,
                              void* d_out, int out_size, void* d_ws,
                              size_t ws_size, hipStream_t stream) {
  const float* x = (const float*)d_in[0];         // [8192, 512] f32
  const float* patterns = (const float*)d_in[1];  // [1024, 512] f32
  const float* edges = (const float*)d_in[2];     // [7] f32
  float* out = (float*)d_out;                     // 16384 f32

  u32* xplanes = (u32*)d_ws;                       // 1.57 MB
  u32* pplanes = xplanes + (size_t)NROW * 48;      // 196 KB
  u32* keys = pplanes + (size_t)NPAT * 48;         // 32 KB

  prep_pc<<<608, 256, 0, stream>>>(x, patterns, edges, xplanes, pplanes, keys);
  match_pc<<<1024, 512, 0, stream>>>(xplanes, pplanes, keys);
  fixup_pc<<<32, 256, 0, stream>>>(keys, out);
}

// Round 8
// 120.808 us; speedup vs baseline: 1.0970x; 1.0970x over previous
//
#include <hip/hip_runtime.h>
#include <stdint.h>

// QuantizedPatternMatcher — R23: bitplane popcount, pair-split, with rp
// PINNED to registers via opaque asm (defeats remat).
//
// R22 post-mortem: VGPR_Count=28 vs designed ~58. rp[24] is a loop-invariant
// load from __restrict__ const memory => the occupancy-greedy backend chose
// to REMATERIALIZE it (reload from vL1 every pattern iteration) instead of
// keeping it live. Loop became load-bound again: VALUBusy 33%, 65us.
// Loads did go VMEM (SGPR=16) — formulation fine, residency not.
//
// R23 changes (one mechanism, two hygiene tweaks):
//  - PIN: asm("" : "+v"(rp[j])) after load => value is compiler-opaque =>
//    non-rematerializable => stays in VGPRs. Live = rp24 + sp24 + misc ~60
//    <= 64, the tier 256-thr blocks reliably get (R18:56, R21:64) => no
//    spill either.
//  - half-combine via DPP quad_perm swap (VALU pipe, no DS/lgkmcnt in loop)
//    instead of __shfl_xor.
//  - block 256 = 128 rows x 2 halves; grid 2048 = 64 rb x 32 pc (pc fast:
//    co-resident blocks spaced 256 = 0 mod 32 share the 6KB vL1 tile).
// R20 calibration: VALU ~4.2cyc/instr @4w/SIMD, better at 8 => match floor
// ~20-25us. Argmax = min-key (mis<<10)|pat via atomicMin (exact ref
// tie-break: max matches then lowest index). Integer-exact end to end.
#define NROW 8192
#define NPAT 1024

typedef unsigned int u32;
typedef unsigned char u8;

__device__ __forceinline__ u32 bin7(float v, float e0, float e1, float e2,
                                    float e3, float e4, float e5, float e6) {
  return (u32)((v > e0) + (v > e1) + (v > e2) + (v > e3) + (v > e4) +
               (v > e5) + (v > e6));
}

__device__ __forceinline__ void acc3(u32 b, int k, u32& p0, u32& p1, u32& p2) {
  p0 |= (b & 1u) << k;
  p1 |= ((b >> 1) & 1u) << k;
  p2 |= ((b >> 2) & 1u) << k;
}

// ---------------------------------------------------------------------------
// prep: quantize + pack bitplanes; init keys (=0xFFFFFFFF).
//   xplanes [8192][16][3] u32   (48 dwords = 192 B per row; per 32-dim chunk
//   pplanes [1024][16][3] u32    the 3 planes are contiguous)
// ---------------------------------------------------------------------------
__global__ __launch_bounds__(256) void prep_pc(
    const float* __restrict__ x, const float* __restrict__ patterns,
    const float* __restrict__ edges, u32* __restrict__ xplanes,
    u32* __restrict__ pplanes, u32* __restrict__ keys) {
  const int bid = blockIdx.x, tid = threadIdx.x;
  if (bid >= 576) {  // 32 blocks: init keys
    const int r = (bid - 576) * 256 + tid;
    keys[r] = 0xFFFFFFFFu;
    return;
  }
  const float e0 = edges[0], e1 = edges[1], e2 = edges[2], e3 = edges[3],
              e4 = edges[4], e5 = edges[5], e6 = edges[6];
  const float4* s4;
  u32* dst;
  if (bid < 512) {  // x: 8192 rows * 16 chunks
    const int i = bid * 256 + tid;
    s4 = reinterpret_cast<const float4*>(x + (size_t)i * 32);
    dst = xplanes + (size_t)i * 3;
  } else {  // patterns: 1024 * 16
    const int j = (bid - 512) * 256 + tid;
    s4 = reinterpret_cast<const float4*>(patterns + (size_t)j * 32);
    dst = pplanes + (size_t)j * 3;
  }
  u32 p0 = 0, p1 = 0, p2 = 0;
#pragma unroll
  for (int q = 0; q < 8; ++q) {
    const float4 a = s4[q];
    acc3(bin7(a.x, e0, e1, e2, e3, e4, e5, e6), q * 4 + 0, p0, p1, p2);
    acc3(bin7(a.y, e0, e1, e2, e3, e4, e5, e6), q * 4 + 1, p0, p1, p2);
    acc3(bin7(a.z, e0, e1, e2, e3, e4, e5, e6), q * 4 + 2, p0, p1, p2);
    acc3(bin7(a.w, e0, e1, e2, e3, e4, e5, e6), q * 4 + 3, p0, p1, p2);
  }
  dst[0] = p0;
  dst[1] = p1;
  dst[2] = p2;
}

// ---------------------------------------------------------------------------
// match: grid 2048 = 64 row-blocks (slow) x 32 pattern-tiles (fast; blocks
// spaced 256 = 0 mod 32 co-resident on a CU share the 6KB tile in vL1).
// 256 thr = 128 rows x 2 halves; 8 blocks/CU = 8 waves/SIMD.
// rp[24] loaded once and PINNED (opaque asm => no remat, no spill: live
// ~60 <= 64-VGPR tier). sp streamed per pattern (in-order vmcnt). Halves
// combined with a DPP quad-perm swap (VALU pipe; no DS op in the loop).
// ---------------------------------------------------------------------------
__global__ __launch_bounds__(256) void match_pc(
    const u32* __restrict__ xplanes, const u32* __restrict__ pplanes,
    u32* __restrict__ keys) {
  const int tid = threadIdx.x;
  const int rb = blockIdx.x >> 5;  // row block, 0..63 (slow)
  const int pc = blockIdx.x & 31;  // pattern tile, 0..31 (fast)
  const int row = rb * 128 + (tid >> 1);
  const int half = tid & 1;

  // Opaque zero: keeps the pattern loads on the VMEM path (in-order vmcnt)
  // regardless of what uniformity analysis concludes.
  u32 z;
  asm("v_mov_b32 %0, 0" : "=v"(z));

  u32 rp[24];
  {
    const u8* __restrict__ rs =
        reinterpret_cast<const u8*>(xplanes + (size_t)row * 48 + half * 24) +
        z;
#pragma unroll
    for (int j = 0; j < 6; ++j) {
      const uint4 v = *reinterpret_cast<const uint4*>(rs + j * 16);
      rp[j * 4 + 0] = v.x;
      rp[j * 4 + 1] = v.y;
      rp[j * 4 + 2] = v.z;
      rp[j * 4 + 3] = v.w;
    }
  }
  // PIN: values become compiler-opaque => cannot be rematerialized from
  // memory; allocator must keep them resident in VGPRs.
#pragma unroll
  for (int j = 0; j < 24; ++j) asm("" : "+v"(rp[j]));

  const u8* __restrict__ pz =
      reinterpret_cast<const u8*>(pplanes + (size_t)pc * (32 * 48) +
                                  half * 24) +
      z;

  u32 best = 0xFFFFFFFFu;
  const u32 pb = (u32)(pc << 5);
#pragma unroll 1
  for (int p = 0; p < 32; ++p) {
    u32 sp[24];
#pragma unroll
    for (int j = 0; j < 6; ++j) {  // 6 VMEM dwordx4; 2 addrs/wave -> vL1
      const uint4 v = *reinterpret_cast<const uint4*>(pz + p * 192 + j * 16);
      sp[j * 4 + 0] = v.x;
      sp[j * 4 + 1] = v.y;
      sp[j * 4 + 2] = v.z;
      sp[j * 4 + 3] = v.w;
    }
    u32 mis = 0;
#pragma unroll
    for (int c = 0; c < 8; ++c) {  // 48 int VALU (bcnt fuses the add)
      const u32 d = (rp[c * 3 + 0] ^ sp[c * 3 + 0]) |
                    (rp[c * 3 + 1] ^ sp[c * 3 + 1]) |
                    (rp[c * 3 + 2] ^ sp[c * 3 + 2]);
      mis += (u32)__popc(d);
    }
    // Combine the two halves: DPP quad_perm [1,0,3,2] swaps lane pairs on
    // the VALU pipe (no DS, no lgkmcnt). Both lanes end with the full sum.
    const u32 other =
        (u32)__builtin_amdgcn_mov_dpp((int)mis, 0xB1, 0xF, 0xF, true);
    mis += other;
    const u32 key = (mis << 10) | (pb + (u32)p);
    best = key < best ? key : best;
  }
  if (half == 0) atomicMin(&keys[row], best);
}

__global__ __launch_bounds__(256) void fixup_pc(const u32* __restrict__ keys,
                                                float* __restrict__ out) {
  const int r = blockIdx.x * 256 + threadIdx.x;
  const u32 k = keys[r];
  out[r] = (float)(k & 1023u);
  out[NROW + r] = (float)(512u - (k >> 10)) * (1.0f / 512.0f);
}

extern "C" void kernel_launch(void* const* d_in, const int* in_sizes, int n_in,
                              void* d_out, int out_size, void* d_ws,
                              size_t ws_size, hipStream_t stream) {
  const float* x = (const float*)d_in[0];         // [8192, 512] f32
  const float* patterns = (const float*)d_in[1];  // [1024, 512] f32
  const float* edges = (const float*)d_in[2];     // [7] f32
  float* out = (float*)d_out;                     // 16384 f32

  u32* xplanes = (u32*)d_ws;                       // 1.57 MB
  u32* pplanes = xplanes + (size_t)NROW * 48;      // 196 KB
  u32* keys = pplanes + (size_t)NPAT * 48;         // 32 KB

  prep_pc<<<608, 256, 0, stream>>>(x, patterns, edges, xplanes, pplanes, keys);
  match_pc<<<2048, 256, 0, stream>>>(xplanes, pplanes, keys);
  fixup_pc<<<32, 256, 0, stream>>>(keys, out);
}